// Round 2
// baseline (1743.866 us; speedup 1.0000x reference)
//
#include <hip/hip_runtime.h>

// ScaledDotProductAttention: B=4 H=16 S=2048 DK=128, fp32 in, int32 mask.
// Outputs (concatenated in d_out): out (B,H,S,DK) fp32 then weights (B,H,S,S) fp32.
//
// R1: hoist fp32->bf16 conversion out of the O(S^2) loops.
//  - prepass A: K -> bf16 [bh][k][d] in ws
//  - prepass B: V -> bf16 hi/lo, TRANSPOSED [bh][d][k] in ws (PV B-frags become 16B loads)
//  - main kernel: QK^T MFMA -> mask/exp -> bf16 P in swizzled LDS -> weights write -> PV MFMA
//  - fallback (ws too small): in-kernel conversion (R0 path)

constexpr int Bc = 4, Hc = 16, Sc = 2048, Dc = 128;
constexpr int BHc = Bc * Hc;           // 64
constexpr int QB = 16;                 // q rows per block
constexpr int NQT = Sc / QB;           // 128
constexpr int NBLK = BHc * NQT;        // 8192
constexpr long OUTE = (long)BHc * Sc * Dc;   // out elements (start of weights region)
constexpr long KVE  = (long)BHc * Sc * Dc;   // elements per K/V plane
#define SCALEF 0.088388347648318447f   // 1/sqrt(128)

typedef __attribute__((ext_vector_type(4))) float f32x4;
typedef __attribute__((ext_vector_type(8))) short bf16x8;
typedef unsigned short ushort_t;

static __device__ __forceinline__ unsigned short f2bf(float f) {
  unsigned u = __float_as_uint(f);
  return (unsigned short)((u + 0x7fffu + ((u >> 16) & 1u)) >> 16);  // RNE
}
static __device__ __forceinline__ float bf2f(unsigned short h) {
  return __uint_as_float(((unsigned)h) << 16);
}
static __device__ __forceinline__ bf16x8 loadcvt8(const float* __restrict__ p) {
  float4 a = *(const float4*)p;
  float4 b = *(const float4*)(p + 4);
  bf16x8 r;
  r[0] = (short)f2bf(a.x); r[1] = (short)f2bf(a.y);
  r[2] = (short)f2bf(a.z); r[3] = (short)f2bf(a.w);
  r[4] = (short)f2bf(b.x); r[5] = (short)f2bf(b.y);
  r[6] = (short)f2bf(b.z); r[7] = (short)f2bf(b.w);
  return r;
}

// ---- prepass A: K fp32 -> bf16, same [bh][k][d] layout. 8 elems/thread.
__global__ __launch_bounds__(256)
void kconv_kernel(const float* __restrict__ K, ushort_t* __restrict__ Kb) {
  long i = ((long)blockIdx.x * 256 + threadIdx.x) * 8;
  bf16x8 v = loadcvt8(K + i);
  *(bf16x8*)(Kb + i) = v;
}

// ---- prepass B: V fp32 [bh][k][d] -> bf16 hi/lo transposed [bh][d][k].
// block handles (bh, 64-k tile); LDS staging for the transpose.
__global__ __launch_bounds__(256)
void vtrans_kernel(const float* __restrict__ V, ushort_t* __restrict__ Vthi,
                   ushort_t* __restrict__ Vtlo) {
  __shared__ ushort2 sT[Dc][64 + 1];   // [d][ki], +1 pad vs bank conflicts (~33 KB)
  const int bh = blockIdx.x >> 5;
  const int kt = blockIdx.x & 31;
  const int tid = threadIdx.x;
  const float* vb = V + ((long)bh * Sc + kt * 64) * Dc;
  #pragma unroll
  for (int i = 0; i < 8; i++) {
    int e = tid + i * 256;            // quad index 0..2047
    int ki = e >> 5;
    int dq = (e & 31) * 4;
    float4 f = *(const float4*)(vb + (long)ki * Dc + dq);
    float fv[4] = {f.x, f.y, f.z, f.w};
    #pragma unroll
    for (int c2 = 0; c2 < 4; c2++) {
      unsigned short h = f2bf(fv[c2]);
      unsigned short l = f2bf(fv[c2] - bf2f(h));
      ushort2 p; p.x = h; p.y = l;
      sT[dq + c2][ki] = p;
    }
  }
  __syncthreads();
  #pragma unroll
  for (int i = 0; i < 4; i++) {
    int chunk = tid + i * 256;        // 0..1023
    int d = chunk >> 3;
    int kc = (chunk & 7) * 8;
    bf16x8 hi, lo;
    #pragma unroll
    for (int j = 0; j < 8; j++) {
      ushort2 p = sT[d][kc + j];
      hi[j] = (short)p.x; lo[j] = (short)p.y;
    }
    long ob = ((long)bh * Dc + d) * Sc + kt * 64 + kc;
    *(bf16x8*)(Vthi + ob) = hi;
    *(bf16x8*)(Vtlo + ob) = lo;
  }
}

template <bool PRE>
__global__ __launch_bounds__(256, 2)
void sdpa_fused_kernel(const float* __restrict__ Qg, const float* __restrict__ Kg,
                       const float* __restrict__ Vg, const int* __restrict__ Mg,
                       float* __restrict__ Og, const ushort_t* __restrict__ Kb,
                       const ushort_t* __restrict__ Vthi, const ushort_t* __restrict__ Vtlo) {
  // LDS: P row buffer, bf16, swizzled: byte = row*4096 + ((col*2) ^ ((row&7)<<4))
  __shared__ __align__(16) unsigned char sP[QB * Sc * 2];  // 65536 B
  __shared__ float sRsum[4][QB];
  __shared__ float sRinv[QB];

  // XCD-chunked swizzle: each XCD gets 1024 consecutive logical blocks (K/V L2-hot per bh)
  const int bid0 = blockIdx.x;
  const int bid  = (bid0 & 7) * (NBLK >> 3) + (bid0 >> 3);
  const int bh = bid >> 7;
  const int qt = bid & (NQT - 1);

  const int tid  = threadIdx.x;
  const int lane = tid & 63;
  const int wave = tid >> 6;
  const int g = lane >> 4;          // 0..3 (k-group of MFMA operand)
  const int c = lane & 15;          // 0..15 (A row / B col / D col)

  const float* Qb = Qg + ((long)bh * Sc + (long)qt * QB) * Dc;

  // ---- Q A-fragments: lane holds Q[qrow=c][d = ch*32 + g*8 + j]
  bf16x8 aq[4];
  {
    const float* qp = Qb + (long)c * Dc + g * 8;
    #pragma unroll
    for (int ch = 0; ch < 4; ch++) aq[ch] = loadcvt8(qp + ch * 32);
  }

  const long mbase = ((long)bh * Sc + (long)qt * QB) * Sc;
  float rs[4] = {0.f, 0.f, 0.f, 0.f};

  // ---- Phase 1: S = QK^T/sqrt(dk), mask, exp -> LDS P (bf16), row-sum partials
  for (int kt = wave; kt < Sc / 16; kt += 4) {
    bf16x8 bk0, bk1, bk2, bk3;
    if constexpr (PRE) {
      const ushort_t* kp = Kb + ((long)bh * Sc + (long)(kt * 16 + c)) * Dc + g * 8;
      bk0 = *(const bf16x8*)kp;
      bk1 = *(const bf16x8*)(kp + 32);
      bk2 = *(const bf16x8*)(kp + 64);
      bk3 = *(const bf16x8*)(kp + 96);
    } else {
      const float* kp = Kg + ((long)bh * Sc + (long)(kt * 16 + c)) * Dc + g * 8;
      bk0 = loadcvt8(kp);
      bk1 = loadcvt8(kp + 32);
      bk2 = loadcvt8(kp + 64);
      bk3 = loadcvt8(kp + 96);
    }
    f32x4 acc = {0.f, 0.f, 0.f, 0.f};
    acc = __builtin_amdgcn_mfma_f32_16x16x32_bf16(aq[0], bk0, acc, 0, 0, 0);
    acc = __builtin_amdgcn_mfma_f32_16x16x32_bf16(aq[1], bk1, acc, 0, 0, 0);
    acc = __builtin_amdgcn_mfma_f32_16x16x32_bf16(aq[2], bk2, acc, 0, 0, 0);
    acc = __builtin_amdgcn_mfma_f32_16x16x32_bf16(aq[3], bk3, acc, 0, 0, 0);
    // D layout: col = c, row = g*4 + r
    const int col = kt * 16 + c;
    const int* mp = Mg + mbase + col;
    #pragma unroll
    for (int r = 0; r < 4; r++) {
      const int row = g * 4 + r;
      const int m = mp[(long)row * Sc];
      float e = (m != 0) ? __expf(acc[r] * SCALEF) : 0.0f;
      unsigned short eb = f2bf(e);
      rs[r] += bf2f(eb);
      *(unsigned short*)(sP + row * (Sc * 2) + ((col * 2) ^ ((row & 7) << 4))) = eb;
    }
  }

  #pragma unroll
  for (int r = 0; r < 4; r++) {
    float x = rs[r];
    x += __shfl_xor(x, 1);
    x += __shfl_xor(x, 2);
    x += __shfl_xor(x, 4);
    x += __shfl_xor(x, 8);
    rs[r] = x;
  }
  if (c == 0) {
    #pragma unroll
    for (int r = 0; r < 4; r++) sRsum[wave][g * 4 + r] = rs[r];
  }
  __syncthreads();
  if (tid < QB) {
    float t = sRsum[0][tid] + sRsum[1][tid] + sRsum[2][tid] + sRsum[3][tid];
    sRinv[tid] = (t > 0.0f) ? (1.0f / t) : 0.0f;
  }
  __syncthreads();

  // ---- Phase 2: weights = P * rinv, coalesced fp32 stores
  {
    float* wb = Og + OUTE + ((long)bh * Sc + (long)qt * QB) * Sc;
    for (int row = 0; row < QB; row++) {
      const float ri = sRinv[row];
      const unsigned char* src = sP + row * (Sc * 2) + ((tid * 16) ^ ((row & 7) << 4));
      bf16x8 pvv = *(const bf16x8*)src;
      float4 w0, w1;
      w0.x = bf2f((unsigned short)pvv[0]) * ri;
      w0.y = bf2f((unsigned short)pvv[1]) * ri;
      w0.z = bf2f((unsigned short)pvv[2]) * ri;
      w0.w = bf2f((unsigned short)pvv[3]) * ri;
      w1.x = bf2f((unsigned short)pvv[4]) * ri;
      w1.y = bf2f((unsigned short)pvv[5]) * ri;
      w1.z = bf2f((unsigned short)pvv[6]) * ri;
      w1.w = bf2f((unsigned short)pvv[7]) * ri;
      float* dst = wb + (long)row * Sc + tid * 8;
      *(float4*)dst = w0;
      *(float4*)(dst + 4) = w1;
    }
  }

  float rinv_r[4];
  #pragma unroll
  for (int r = 0; r < 4; r++) rinv_r[r] = sRinv[g * 4 + r];

  // ---- Phase 3: out = P V. A-frag from LDS P; V hi/lo bf16 from transposed ws (16B loads).
  f32x4 o0 = {0.f, 0.f, 0.f, 0.f}, o1 = {0.f, 0.f, 0.f, 0.f};
  const int n0c = (wave * 2) * 16 + c;
  const int n1c = (wave * 2 + 1) * 16 + c;
  #pragma unroll 2
  for (int kk = 0; kk < Sc / 32; kk++) {
    const int abyte = c * (Sc * 2) + (((kk * 64) + g * 16) ^ ((c & 7) << 4));
    bf16x8 af = *(const bf16x8*)(sP + abyte);
    bf16x8 bh0, bl0, bh1, bl1;
    if constexpr (PRE) {
      const long koff = kk * 32 + g * 8;
      const ushort_t* v0h = Vthi + ((long)bh * Dc + n0c) * Sc + koff;
      const ushort_t* v1h = Vthi + ((long)bh * Dc + n1c) * Sc + koff;
      const ushort_t* v0l = Vtlo + ((long)bh * Dc + n0c) * Sc + koff;
      const ushort_t* v1l = Vtlo + ((long)bh * Dc + n1c) * Sc + koff;
      bh0 = *(const bf16x8*)v0h;
      bh1 = *(const bf16x8*)v1h;
      bl0 = *(const bf16x8*)v0l;
      bl1 = *(const bf16x8*)v1l;
    } else {
      const float* vp = Vg + (long)bh * Sc * Dc + (long)(kk * 32 + g * 8) * Dc;
      #pragma unroll
      for (int j = 0; j < 8; j++) {
        float v0 = vp[(long)j * Dc + n0c];
        float v1 = vp[(long)j * Dc + n1c];
        unsigned short h0 = f2bf(v0);
        unsigned short h1 = f2bf(v1);
        bh0[j] = (short)h0; bl0[j] = (short)f2bf(v0 - bf2f(h0));
        bh1[j] = (short)h1; bl1[j] = (short)f2bf(v1 - bf2f(h1));
      }
    }
    o0 = __builtin_amdgcn_mfma_f32_16x16x32_bf16(af, bh0, o0, 0, 0, 0);
    o0 = __builtin_amdgcn_mfma_f32_16x16x32_bf16(af, bl0, o0, 0, 0, 0);
    o1 = __builtin_amdgcn_mfma_f32_16x16x32_bf16(af, bh1, o1, 0, 0, 0);
    o1 = __builtin_amdgcn_mfma_f32_16x16x32_bf16(af, bl1, o1, 0, 0, 0);
  }

  float* ob = Og + ((long)bh * Sc + (long)qt * QB) * Dc;
  #pragma unroll
  for (int r = 0; r < 4; r++) {
    const int row = g * 4 + r;
    ob[(long)row * Dc + n0c] = o0[r] * rinv_r[r];
    ob[(long)row * Dc + n1c] = o1[r] * rinv_r[r];
  }
}

extern "C" void kernel_launch(void* const* d_in, const int* in_sizes, int n_in,
                              void* d_out, int out_size, void* d_ws, size_t ws_size,
                              hipStream_t stream) {
  (void)in_sizes; (void)n_in; (void)out_size;
  const float* q = (const float*)d_in[0];
  const float* k = (const float*)d_in[1];
  const float* v = (const float*)d_in[2];
  const int* m = (const int*)d_in[3];
  float* out = (float*)d_out;

  const size_t need = 3UL * KVE * sizeof(ushort_t);  // K bf16 + Vt hi + Vt lo = 100.7 MB
  if (d_ws != nullptr && ws_size >= need) {
    ushort_t* Kb   = (ushort_t*)d_ws;
    ushort_t* Vthi = Kb + KVE;
    ushort_t* Vtlo = Vthi + KVE;
    hipLaunchKernelGGL(kconv_kernel, dim3((int)(KVE / 8 / 256)), dim3(256), 0, stream, k, Kb);
    hipLaunchKernelGGL(vtrans_kernel, dim3(BHc * 32), dim3(256), 0, stream, v, Vthi, Vtlo);
    hipLaunchKernelGGL((sdpa_fused_kernel<true>), dim3(NBLK), dim3(256), 0, stream,
                       q, k, v, m, out, Kb, Vthi, Vtlo);
  } else {
    hipLaunchKernelGGL((sdpa_fused_kernel<false>), dim3(NBLK), dim3(256), 0, stream,
                       q, k, v, m, out, nullptr, nullptr, nullptr);
  }
}

// Round 3
// 1179.163 us; speedup vs baseline: 1.4789x; 1.4789x over previous
//
#include <hip/hip_runtime.h>

// ScaledDotProductAttention: B=4 H=16 S=2048 DK=128, fp32 in, int32 mask.
// Outputs (concatenated in d_out): out (B,H,S,DK) fp32 then weights (B,H,S,S) fp32.
//
// R2: attack latency-bound regime (R1: all pipes <15% busy, occupancy 23.7%).
//  - 512-thread blocks (8 waves), same 64KB P buffer -> 16 waves/CU (2x occupancy)
//  - fp16 everywhere (Q,K,V,P): drops the V hi/lo split -> phase-3 loads+MFMAs halve,
//    and fp16's 10-bit mantissa beats bf16 by 8x on error
//  - manual mask prefetch (next k-tile's mask loads issued before current MFMA block)
//  - prepass: K fp32->fp16 [bh][k][d]; V fp32->fp16 transposed [bh][d][k]

constexpr int Bc = 4, Hc = 16, Sc = 2048, Dc = 128;
constexpr int BHc = Bc * Hc;           // 64
constexpr int QB = 16;                 // q rows per block
constexpr int NQT = Sc / QB;           // 128
constexpr int NBLK = BHc * NQT;        // 8192
constexpr long OUTE = (long)BHc * Sc * Dc;   // out elements (start of weights region)
constexpr long KVE  = (long)BHc * Sc * Dc;   // elements per K/V plane
#define SCALEF 0.088388347648318447f   // 1/sqrt(128)

typedef __attribute__((ext_vector_type(4))) float f32x4;
typedef _Float16 f16x8 __attribute__((ext_vector_type(8)));
typedef _Float16 f16x4 __attribute__((ext_vector_type(4)));
typedef unsigned short ushort_t;

static __device__ __forceinline__ f16x8 loadcvt8h(const float* __restrict__ p) {
  float4 a = *(const float4*)p;
  float4 b = *(const float4*)(p + 4);
  f16x8 r;
  r[0] = (_Float16)a.x; r[1] = (_Float16)a.y; r[2] = (_Float16)a.z; r[3] = (_Float16)a.w;
  r[4] = (_Float16)b.x; r[5] = (_Float16)b.y; r[6] = (_Float16)b.z; r[7] = (_Float16)b.w;
  return r;
}

// ---- prepass A: K fp32 -> fp16, same [bh][k][d] layout. 8 elems/thread.
__global__ __launch_bounds__(256)
void kconv_kernel(const float* __restrict__ K, _Float16* __restrict__ Kh) {
  long i = ((long)blockIdx.x * 256 + threadIdx.x) * 8;
  f16x8 v = loadcvt8h(K + i);
  *(f16x8*)(Kh + i) = v;
}

// ---- prepass B: V fp32 [bh][k][d] -> fp16 transposed [bh][d][k].
__global__ __launch_bounds__(256)
void vtrans_kernel(const float* __restrict__ V, _Float16* __restrict__ Vt) {
  __shared__ _Float16 sT[Dc][64 + 2];   // [d][ki], pad vs bank conflicts (~16.5 KB)
  const int bh = blockIdx.x >> 5;
  const int kt = blockIdx.x & 31;
  const int tid = threadIdx.x;
  const float* vb = V + ((long)bh * Sc + kt * 64) * Dc;
  #pragma unroll
  for (int i = 0; i < 8; i++) {
    int e = tid + i * 256;            // quad index 0..2047
    int ki = e >> 5;
    int dq = (e & 31) * 4;
    float4 f = *(const float4*)(vb + (long)ki * Dc + dq);
    sT[dq + 0][ki] = (_Float16)f.x;
    sT[dq + 1][ki] = (_Float16)f.y;
    sT[dq + 2][ki] = (_Float16)f.z;
    sT[dq + 3][ki] = (_Float16)f.w;
  }
  __syncthreads();
  #pragma unroll
  for (int i = 0; i < 4; i++) {
    int chunk = tid + i * 256;        // 0..1023
    int d = chunk >> 3;
    int kc = (chunk & 7) * 8;
    f16x8 o;
    #pragma unroll
    for (int j = 0; j < 8; j++) o[j] = sT[d][kc + j];
    *(f16x8*)(Vt + ((long)bh * Dc + d) * Sc + kt * 64 + kc) = o;
  }
}

template <bool PRE>
__global__ __launch_bounds__(512, 4)
void sdpa_fused_kernel(const float* __restrict__ Qg, const float* __restrict__ Kg,
                       const float* __restrict__ Vg, const int* __restrict__ Mg,
                       float* __restrict__ Og, const _Float16* __restrict__ Kh,
                       const _Float16* __restrict__ Vt) {
  // LDS: P row buffer, fp16, swizzled: byte = row*4096 + ((col*2) ^ ((row&7)<<4))
  __shared__ __align__(16) unsigned char sP[QB * Sc * 2];  // 65536 B
  __shared__ float sRsum[8][QB];
  __shared__ float sRinv[QB];

  // XCD-chunked swizzle: each XCD gets 1024 consecutive logical blocks (K/V L2-hot per bh)
  const int bid0 = blockIdx.x;
  const int bid  = (bid0 & 7) * (NBLK >> 3) + (bid0 >> 3);
  const int bh = bid >> 7;
  const int qt = bid & (NQT - 1);

  const int tid  = threadIdx.x;
  const int lane = tid & 63;
  const int wave = tid >> 6;        // 0..7
  const int g = lane >> 4;          // 0..3 (k-group of MFMA operand)
  const int c = lane & 15;          // 0..15 (A row / B col / D col)

  // ---- Q A-fragments: lane holds Q[qrow=c][d = ch*32 + g*8 + j]
  f16x8 aq[4];
  {
    const float* qp = Qg + ((long)bh * Sc + (long)qt * QB + c) * Dc + g * 8;
    #pragma unroll
    for (int ch = 0; ch < 4; ch++) aq[ch] = loadcvt8h(qp + ch * 32);
  }

  const long mbase = ((long)bh * Sc + (long)qt * QB) * Sc;
  float rs[4] = {0.f, 0.f, 0.f, 0.f};

  // ---- Phase 1: S = QK^T/sqrt(dk), mask, exp -> LDS P (fp16), row-sum partials.
  // 8 waves stride the 128 k-tiles; mask for tile kt+8 prefetched during tile kt.
  int mcur[4];
  {
    const int* mp = Mg + mbase + (wave * 16 + c);
    #pragma unroll
    for (int r = 0; r < 4; r++) mcur[r] = mp[(long)(g * 4 + r) * Sc];
  }
  for (int kt = wave; kt < Sc / 16; kt += 8) {
    int mnext[4] = {0, 0, 0, 0};
    if (kt + 8 < Sc / 16) {
      const int* mp = Mg + mbase + ((kt + 8) * 16 + c);
      #pragma unroll
      for (int r = 0; r < 4; r++) mnext[r] = mp[(long)(g * 4 + r) * Sc];
    }
    f16x8 bk0, bk1, bk2, bk3;
    if constexpr (PRE) {
      const _Float16* kp = Kh + ((long)bh * Sc + (long)(kt * 16 + c)) * Dc + g * 8;
      bk0 = *(const f16x8*)kp;
      bk1 = *(const f16x8*)(kp + 32);
      bk2 = *(const f16x8*)(kp + 64);
      bk3 = *(const f16x8*)(kp + 96);
    } else {
      const float* kp = Kg + ((long)bh * Sc + (long)(kt * 16 + c)) * Dc + g * 8;
      bk0 = loadcvt8h(kp);
      bk1 = loadcvt8h(kp + 32);
      bk2 = loadcvt8h(kp + 64);
      bk3 = loadcvt8h(kp + 96);
    }
    f32x4 acc = {0.f, 0.f, 0.f, 0.f};
    acc = __builtin_amdgcn_mfma_f32_16x16x32_f16(aq[0], bk0, acc, 0, 0, 0);
    acc = __builtin_amdgcn_mfma_f32_16x16x32_f16(aq[1], bk1, acc, 0, 0, 0);
    acc = __builtin_amdgcn_mfma_f32_16x16x32_f16(aq[2], bk2, acc, 0, 0, 0);
    acc = __builtin_amdgcn_mfma_f32_16x16x32_f16(aq[3], bk3, acc, 0, 0, 0);
    // D layout: col = c, row = g*4 + r
    const int col = kt * 16 + c;
    #pragma unroll
    for (int r = 0; r < 4; r++) {
      const int row = g * 4 + r;
      float e = (mcur[r] != 0) ? __expf(acc[r] * SCALEF) : 0.0f;
      _Float16 eh = (_Float16)e;
      rs[r] += (float)eh;   // accumulate fp16-rounded value so weights sum ~exactly to 1
      *(_Float16*)(sP + row * (Sc * 2) + ((col * 2) ^ ((row & 7) << 4))) = eh;
      mcur[r] = mnext[r];
    }
  }

  #pragma unroll
  for (int r = 0; r < 4; r++) {
    float x = rs[r];
    x += __shfl_xor(x, 1);
    x += __shfl_xor(x, 2);
    x += __shfl_xor(x, 4);
    x += __shfl_xor(x, 8);
    rs[r] = x;
  }
  if (c == 0) {
    #pragma unroll
    for (int r = 0; r < 4; r++) sRsum[wave][g * 4 + r] = rs[r];
  }
  __syncthreads();
  if (tid < QB) {
    float t = 0.f;
    #pragma unroll
    for (int w = 0; w < 8; w++) t += sRsum[w][tid];
    sRinv[tid] = (t > 0.0f) ? (1.0f / t) : 0.0f;
  }
  __syncthreads();

  // ---- Phase 2: weights = P * rinv. Thread t -> cols 4t..4t+3, coalesced float4 stores.
  {
    float* wb = Og + OUTE + ((long)bh * Sc + (long)qt * QB) * Sc;
    for (int row = 0; row < QB; row++) {
      const float ri = sRinv[row];
      const unsigned char* src = sP + row * (Sc * 2) + ((tid * 8) ^ ((row & 7) << 4));
      f16x4 pv = *(const f16x4*)src;
      float4 w;
      w.x = (float)pv[0] * ri;
      w.y = (float)pv[1] * ri;
      w.z = (float)pv[2] * ri;
      w.w = (float)pv[3] * ri;
      *(float4*)(wb + (long)row * Sc + tid * 4) = w;
    }
  }

  float rinv_r[4];
  #pragma unroll
  for (int r = 0; r < 4; r++) rinv_r[r] = sRinv[g * 4 + r];

  // ---- Phase 3: out = P V. A-frag from LDS P; B-frag = Vt 16B loads. One 16-col
  // n-tile per wave; two interleaved accumulators to relax the MFMA dep chain.
  f32x4 oa = {0.f, 0.f, 0.f, 0.f}, ob2 = {0.f, 0.f, 0.f, 0.f};
  const int nc = wave * 16 + c;     // d column
  const _Float16* vbase = Vt + ((long)bh * Dc + nc) * Sc + g * 8;
  #pragma unroll 2
  for (int kk = 0; kk < Sc / 32; kk += 2) {
    const int ab0 = c * (Sc * 2) + (((kk * 64) + g * 16) ^ ((c & 7) << 4));
    const int ab1 = c * (Sc * 2) + (((kk * 64 + 64) + g * 16) ^ ((c & 7) << 4));
    f16x8 af0 = *(const f16x8*)(sP + ab0);
    f16x8 af1 = *(const f16x8*)(sP + ab1);
    f16x8 bv0 = *(const f16x8*)(vbase + kk * 32);
    f16x8 bv1 = *(const f16x8*)(vbase + kk * 32 + 32);
    oa  = __builtin_amdgcn_mfma_f32_16x16x32_f16(af0, bv0, oa, 0, 0, 0);
    ob2 = __builtin_amdgcn_mfma_f32_16x16x32_f16(af1, bv1, ob2, 0, 0, 0);
  }

  float* ob = Og + ((long)bh * Sc + (long)qt * QB) * Dc;
  #pragma unroll
  for (int r = 0; r < 4; r++) {
    const int row = g * 4 + r;
    ob[(long)row * Dc + nc] = (oa[r] + ob2[r]) * rinv_r[r];
  }
}

// fallback phase-3 V gather path shares the template; non-PRE converts in-kernel.
template <>
__global__ __launch_bounds__(512, 4)
void sdpa_fused_kernel<false>(const float* __restrict__ Qg, const float* __restrict__ Kg,
                              const float* __restrict__ Vg, const int* __restrict__ Mg,
                              float* __restrict__ Og, const _Float16* __restrict__ Kh,
                              const _Float16* __restrict__ Vt) {
  __shared__ __align__(16) unsigned char sP[QB * Sc * 2];
  __shared__ float sRsum[8][QB];
  __shared__ float sRinv[QB];
  const int bid0 = blockIdx.x;
  const int bid  = (bid0 & 7) * (NBLK >> 3) + (bid0 >> 3);
  const int bh = bid >> 7;
  const int qt = bid & (NQT - 1);
  const int tid  = threadIdx.x;
  const int lane = tid & 63;
  const int wave = tid >> 6;
  const int g = lane >> 4;
  const int c = lane & 15;

  f16x8 aq[4];
  {
    const float* qp = Qg + ((long)bh * Sc + (long)qt * QB + c) * Dc + g * 8;
    #pragma unroll
    for (int ch = 0; ch < 4; ch++) aq[ch] = loadcvt8h(qp + ch * 32);
  }
  const long mbase = ((long)bh * Sc + (long)qt * QB) * Sc;
  float rs[4] = {0.f, 0.f, 0.f, 0.f};
  for (int kt = wave; kt < Sc / 16; kt += 8) {
    const float* kp = Kg + ((long)bh * Sc + (long)(kt * 16 + c)) * Dc + g * 8;
    f16x8 bk0 = loadcvt8h(kp);
    f16x8 bk1 = loadcvt8h(kp + 32);
    f16x8 bk2 = loadcvt8h(kp + 64);
    f16x8 bk3 = loadcvt8h(kp + 96);
    f32x4 acc = {0.f, 0.f, 0.f, 0.f};
    acc = __builtin_amdgcn_mfma_f32_16x16x32_f16(aq[0], bk0, acc, 0, 0, 0);
    acc = __builtin_amdgcn_mfma_f32_16x16x32_f16(aq[1], bk1, acc, 0, 0, 0);
    acc = __builtin_amdgcn_mfma_f32_16x16x32_f16(aq[2], bk2, acc, 0, 0, 0);
    acc = __builtin_amdgcn_mfma_f32_16x16x32_f16(aq[3], bk3, acc, 0, 0, 0);
    const int col = kt * 16 + c;
    const int* mp = Mg + mbase + col;
    #pragma unroll
    for (int r = 0; r < 4; r++) {
      const int row = g * 4 + r;
      const int m = mp[(long)row * Sc];
      float e = (m != 0) ? __expf(acc[r] * SCALEF) : 0.0f;
      _Float16 eh = (_Float16)e;
      rs[r] += (float)eh;
      *(_Float16*)(sP + row * (Sc * 2) + ((col * 2) ^ ((row & 7) << 4))) = eh;
    }
  }
  #pragma unroll
  for (int r = 0; r < 4; r++) {
    float x = rs[r];
    x += __shfl_xor(x, 1);
    x += __shfl_xor(x, 2);
    x += __shfl_xor(x, 4);
    x += __shfl_xor(x, 8);
    rs[r] = x;
  }
  if (c == 0) {
    #pragma unroll
    for (int r = 0; r < 4; r++) sRsum[wave][g * 4 + r] = rs[r];
  }
  __syncthreads();
  if (tid < QB) {
    float t = 0.f;
    #pragma unroll
    for (int w = 0; w < 8; w++) t += sRsum[w][tid];
    sRinv[tid] = (t > 0.0f) ? (1.0f / t) : 0.0f;
  }
  __syncthreads();
  {
    float* wb = Og + OUTE + ((long)bh * Sc + (long)qt * QB) * Sc;
    for (int row = 0; row < QB; row++) {
      const float ri = sRinv[row];
      const unsigned char* src = sP + row * (Sc * 2) + ((tid * 8) ^ ((row & 7) << 4));
      f16x4 pv = *(const f16x4*)src;
      float4 w;
      w.x = (float)pv[0] * ri;
      w.y = (float)pv[1] * ri;
      w.z = (float)pv[2] * ri;
      w.w = (float)pv[3] * ri;
      *(float4*)(wb + (long)row * Sc + tid * 4) = w;
    }
  }
  float rinv_r[4];
  #pragma unroll
  for (int r = 0; r < 4; r++) rinv_r[r] = sRinv[g * 4 + r];
  f32x4 oa = {0.f, 0.f, 0.f, 0.f};
  const int nc = wave * 16 + c;
  for (int kk = 0; kk < Sc / 32; kk++) {
    const int abyte = c * (Sc * 2) + (((kk * 64) + g * 16) ^ ((c & 7) << 4));
    f16x8 af = *(const f16x8*)(sP + abyte);
    const float* vp = Vg + (long)bh * Sc * Dc + (long)(kk * 32 + g * 8) * Dc + nc;
    f16x8 bv;
    #pragma unroll
    for (int j = 0; j < 8; j++) bv[j] = (_Float16)vp[(long)j * Dc];
    oa = __builtin_amdgcn_mfma_f32_16x16x32_f16(af, bv, oa, 0, 0, 0);
  }
  float* ob = Og + ((long)bh * Sc + (long)qt * QB) * Dc;
  #pragma unroll
  for (int r = 0; r < 4; r++) {
    const int row = g * 4 + r;
    ob[(long)row * Dc + nc] = oa[r] * rinv_r[r];
  }
}

extern "C" void kernel_launch(void* const* d_in, const int* in_sizes, int n_in,
                              void* d_out, int out_size, void* d_ws, size_t ws_size,
                              hipStream_t stream) {
  (void)in_sizes; (void)n_in; (void)out_size;
  const float* q = (const float*)d_in[0];
  const float* k = (const float*)d_in[1];
  const float* v = (const float*)d_in[2];
  const int* m = (const int*)d_in[3];
  float* out = (float*)d_out;

  const size_t need = 2UL * KVE * sizeof(_Float16);  // K fp16 + Vt fp16 = 67 MB
  if (d_ws != nullptr && ws_size >= need) {
    _Float16* Kh = (_Float16*)d_ws;
    _Float16* Vt = Kh + KVE;
    hipLaunchKernelGGL(kconv_kernel, dim3((int)(KVE / 8 / 256)), dim3(256), 0, stream, k, Kh);
    hipLaunchKernelGGL(vtrans_kernel, dim3(BHc * 32), dim3(256), 0, stream, v, Vt);
    hipLaunchKernelGGL((sdpa_fused_kernel<true>), dim3(NBLK), dim3(512), 0, stream,
                       q, k, v, m, out, Kh, Vt);
  } else {
    hipLaunchKernelGGL((sdpa_fused_kernel<false>), dim3(NBLK), dim3(512), 0, stream,
                       q, k, v, m, out, nullptr, nullptr);
  }
}